// Round 14
// baseline (242.327 us; speedup 1.0000x reference)
//
#include <hip/hip_runtime.h>
#include <stdint.h>

// ---------- problem constants ----------
#define S_LEN   2048
#define D_MODEL 2048
#define NH      32
#define NKV     8
#define HDIM    64
#define WIN     1024
#define QKV_N   3072
#define MTOT    4096          // B*S
#define QSCALE  0.18033688011112042f   // 0.125 * log2(e)

typedef __bf16 bf16x8 __attribute__((ext_vector_type(8)));
typedef float  f32x4  __attribute__((ext_vector_type(4)));
typedef float  f32x16 __attribute__((ext_vector_type(16)));
typedef unsigned short u16x8 __attribute__((ext_vector_type(8)));
typedef unsigned short u16x4 __attribute__((ext_vector_type(4)));

#define GLDS16(g, l) __builtin_amdgcn_global_load_lds( \
    (__attribute__((address_space(1))) void*)(g),      \
    (__attribute__((address_space(3))) void*)(l), 16, 0, 0)

// RNE f32->bf16 via the compiler cast (v_cvt_pk fusion).
__device__ __forceinline__ unsigned short f2bf(float f) {
  __bf16 b = (__bf16)f;
  return __builtin_bit_cast(unsigned short, b);
}

// ---------- fp32 -> bf16 conversion (3 segments, vectorized) ----------
__global__ void cvt3(const float* __restrict__ s0, unsigned short* __restrict__ d0, int n0,
                     const float* __restrict__ s1, unsigned short* __restrict__ d1, int n1,
                     const float* __restrict__ s2, unsigned short* __restrict__ d2, int n2)
{
  int total4 = (n0 + n1 + n2) >> 2;
  for (int idx = blockIdx.x * blockDim.x + threadIdx.x; idx < total4;
       idx += gridDim.x * blockDim.x) {
    int i = idx << 2;
    const float* s; unsigned short* d;
    if (i < n0)            { s = s0 + i;            d = d0 + i; }
    else if (i < n0 + n1)  { s = s1 + (i - n0);     d = d1 + (i - n0); }
    else                   { s = s2 + (i - n0 - n1); d = d2 + (i - n0 - n1); }
    float4 v = *(const float4*)s;
    u16x4 o;
    o[0] = f2bf(v.x); o[1] = f2bf(v.y); o[2] = f2bf(v.z); o[3] = f2bf(v.w);
    *(u16x4*)d = o;
  }
}

// ---------- NT GEMM: C[m,n] = sum_k A[m,k]*B[n,k] (+bias) ----------
// EP==0: QKV epilogue (scatter Q scaled / K row-major / V TRANSPOSED [d][s]).
// EP==1: fp32 out.
template<int EP>
__global__ __launch_bounds__(256)
void gemm_nt(const unsigned short* __restrict__ A, const unsigned short* __restrict__ Bm,
             const float* __restrict__ bias, int K, int N,
             unsigned short* __restrict__ qo, unsigned short* __restrict__ ko,
             unsigned short* __restrict__ vo, float* __restrict__ co)
{
  __shared__ unsigned short sA[128 * 32];
  __shared__ unsigned short sB[128 * 32];
  const int t = threadIdx.x;
  const int l = t & 63;
  const int brow = blockIdx.y << 7;
  const int bcol = blockIdx.x << 7;
  const int wr = ((t >> 7) & 1) << 6;
  const int wc = ((t >> 6) & 1) << 6;

  const int srow  = t >> 2;
  const int skoff = (t & 3) << 3;
  const unsigned short* aP = A + (size_t)(brow + srow) * K + skoff;
  const unsigned short* bP = Bm + (size_t)(bcol + srow) * K + skoff;
  unsigned short* ldsA0 = &sA[(t & 192) << 3];
  unsigned short* ldsA1 = &sA[(256 + (t & 192)) << 3];
  unsigned short* ldsB0 = &sB[(t & 192) << 3];
  unsigned short* ldsB1 = &sB[(256 + (t & 192)) << 3];

  f32x4 acc[4][4] = {};
  const int fr = l & 15;
  const int fk = (l >> 4) << 3;

  for (int kt = 0; kt < K; kt += 32) {
    GLDS16(aP, ldsA0);
    GLDS16(aP + (size_t)64 * K, ldsA1);
    GLDS16(bP, ldsB0);
    GLDS16(bP + (size_t)64 * K, ldsB1);
    aP += 32; bP += 32;
    __syncthreads();

    bf16x8 af[4], bf[4];
#pragma unroll
    for (int mi = 0; mi < 4; ++mi)
      af[mi] = *(const bf16x8*)&sA[(wr + mi * 16 + fr) * 32 + fk];
#pragma unroll
    for (int ni = 0; ni < 4; ++ni)
      bf[ni] = *(const bf16x8*)&sB[(wc + ni * 16 + fr) * 32 + fk];
#pragma unroll
    for (int mi = 0; mi < 4; ++mi)
#pragma unroll
      for (int ni = 0; ni < 4; ++ni)
        acc[mi][ni] = __builtin_amdgcn_mfma_f32_16x16x32_bf16(af[mi], bf[ni], acc[mi][ni], 0, 0, 0);
    __syncthreads();
  }

  const int fq4 = (l >> 4) << 2;
  if (EP == 0) {
#pragma unroll
    for (int ni = 0; ni < 4; ++ni) {
      const int e = bcol + wc + ni * 16 + fr;
      const float bs = bias[e];
#pragma unroll
      for (int mi = 0; mi < 4; ++mi) {
#pragma unroll
        for (int j = 0; j < 4; ++j) {
          const int m = brow + wr + mi * 16 + fq4 + j;
          const int b = m >> 11, s = m & 2047;
          float v = acc[mi][ni][j] + bs;
          const int d = e & 63;
          if (e < 2048) {
            const int h = e >> 6;
            qo[(((size_t)b * NH + h) * S_LEN + s) * HDIM + d] = f2bf(v * QSCALE);
          } else if (e < 2560) {
            const int gg = (e - 2048) >> 6;
            ko[(((size_t)b * NKV + gg) * S_LEN + s) * HDIM + d] = f2bf(v);
          } else {
            const int gg = (e - 2560) >> 6;
            // V transposed: Vt[b][g][d][s]
            vo[(((size_t)b * NKV + gg) * HDIM + d) * S_LEN + s] = f2bf(v);
          }
        }
      }
    }
  } else {
#pragma unroll
    for (int mi = 0; mi < 4; ++mi)
#pragma unroll
      for (int j = 0; j < 4; ++j) {
        const int m = brow + wr + mi * 16 + fq4 + j;
#pragma unroll
        for (int ni = 0; ni < 4; ++ni) {
          const int n = bcol + wc + ni * 16 + fr;
          co[(size_t)m * N + n] = acc[mi][ni][j] + bias[n];
        }
      }
  }
}

// ---------- sliding-window flash attention, v11: 32x32 MFMA ----------
// Block = 128q x 64k, 512 thr = 8 waves (qh = w&3 -> rows 32qh..+31,
// kh = w>>2 -> keys 32kh..+31). mfma_f32_32x32x16_bf16:
//   C layout (HW-verified m74/m101): col = lane&31, row = (r&3)+8(r>>2)+4*hi
//   A/B k-mapping (by K-doubling analogy): k = 8*hi + e
// Swapped QK (A=K,B=Q) -> lane holds 16 scores for q = lane&31.
// Staged-K permutation p(sl)=16*sl4+8*sl2+4*sl3+2*sl1+sl0 (bit2<->bit3)
// makes score reg r = 8*m1+e hold phys key 16*m1+8*hi+e -> P packs
// IN REGISTER as the PV A-fragment (keys 8hi+e of k-slice m1).
// Per block-tile LDS reads: 64 b128 for 128q (v10b: 64 for 64q) -> pipe/q halves.
// kh-merge epilogue as in v10b (alpha=exp2(m-mf) self-heals masked halves).
__global__ __launch_bounds__(512)
void attn_swin(const unsigned short* __restrict__ Qs, const unsigned short* __restrict__ Kb,
               const unsigned short* __restrict__ Vtb, unsigned short* __restrict__ ctx)
{
  __shared__ char lds[34816];   // 2 x (K 8KB + V 8KB) staging; reused for merge

  const int t = threadIdx.x, w = t >> 6, l = t & 63;
  const int lq = l & 31, hi = l >> 5;
  const int qh = w & 3, kh = w >> 2;
  const int q0 = blockIdx.x << 7;
  const int h = blockIdx.y, b = blockIdx.z;
  const int g = h >> 2;

  // Q fragments (B-operand): col q = 32qh+lq, k(d) = 16c + 8hi + e
  const unsigned short* qp = Qs + (((size_t)(b * NH + h)) * S_LEN + q0 + (qh << 5) + lq) * HDIM;
  bf16x8 qf[4];
#pragma unroll
  for (int c = 0; c < 4; ++c)
    qf[c] = *(const bf16x8*)(qp + (c << 4) + (hi << 3));

  const unsigned short* Kg  = Kb  + ((size_t)(b * NKV + g)) * S_LEN * HDIM;  // [s][d]
  const unsigned short* Vtg = Vtb + ((size_t)(b * NKV + g)) * HDIM * S_LEN;  // [d][s]

  float m_run = -1e30f, l_part = 0.0f;   // per-lane; q = q0+32qh+lq
  f32x16 o_acc[2] = {};                  // [dt]: d = 32dt+lq, q spread over regs

  int lo = q0 - (WIN - 1); if (lo < 0) lo = 0; lo &= ~63;
  const int hi2 = q0 + 128;
  const int full_lo = q0 - (WIN - 128);  // kv0 >= this: lower bound ok all rows
  const int full_hi = q0 - 64;           // kv0 <= this: j<=i ok all rows

  // ---- staging sources (2 GLDS16 x 1KB per wave): waves 0-3 K, 4-7 V ----
  const unsigned short* src0;
  const unsigned short* src1;
  {
    const int x0 = ((w & 3) << 11) + (l << 4);
    const int x1 = x0 + 1024;
    if (w < 4) {
      const int s0 = x0 >> 7, sl0 = s0 & 31;
      const int s1 = x1 >> 7, sl1 = s1 & 31;
      const int p0 = ((s0 >> 5) << 5) + (sl0 & 16) + ((sl0 & 4) << 1) + ((sl0 & 8) >> 1) + (sl0 & 3);
      const int p1 = ((s1 >> 5) << 5) + (sl1 & 16) + ((sl1 & 4) << 1) + ((sl1 & 8) >> 1) + (sl1 & 3);
      const int o0 = (x0 & 127) ^ ((s0 & 7) << 4);
      const int o1 = (x1 & 127) ^ ((s1 & 7) << 4);
      src0 = Kg + (size_t)(lo + p0) * HDIM + (o0 >> 1);
      src1 = Kg + (size_t)(lo + p1) * HDIM + (o1 >> 1);
    } else {
      const int d0 = x0 >> 7, d1 = x1 >> 7;
      const int o0 = (x0 & 127) ^ ((d0 & 7) << 4);
      const int o1 = (x1 & 127) ^ ((d1 & 7) << 4);
      src0 = Vtg + (size_t)d0 * S_LEN + lo + (o0 >> 1);
      src1 = Vtg + (size_t)d1 * S_LEN + lo + (o1 >> 1);
    }
  }
  const int sadv = (w < 4) ? 64 * HDIM : 64;
  const int dbase = ((w < 4) ? 0 : 8192) + ((w & 3) << 11) + (l << 4);

  char* bufA = lds;
  char* bufB = lds + 16384;

  // prologue: stage tile 0
  GLDS16(src0, bufA + dbase);
  GLDS16(src1, bufA + dbase + 1024);
  src0 += sadv; src1 += sadv;

  const int iq = q0 + (qh << 5) + lq;    // this lane's q-row
  const int swz = (lq & 7) << 4;         // read-side XOR swizzle (slot&7 == d&7 == lq&7)
  const int kbase = (((kh << 5) + lq) << 7) + (hi << 4);

  auto TILE = [&](int kv0, const char* sK, const char* sV, bool MASKED)
      __attribute__((always_inline)) {
    // ---- K A-frags: row = slot 32kh+lq, k(d) = 16c + 8hi + e ----
    bf16x8 kf[4];
#pragma unroll
    for (int c = 0; c < 4; ++c)
      kf[c] = *(const bf16x8*)(sK + ((kbase + (c << 5)) ^ swz));
    // ---- QK^T: C[slot][q], accumulate over d ----
    __builtin_amdgcn_s_setprio(1);
    f32x16 sf = {};
#pragma unroll
    for (int c = 0; c < 4; ++c)
      sf = __builtin_amdgcn_mfma_f32_32x32x16_bf16(kf[c], qf[c], sf, 0, 0, 0);
    __builtin_amdgcn_s_setprio(0);
    // score reg r (=8*m1+e) holds phys key kv0 + 32kh + 16*(r>>3) + 8*hi + (r&7)
    if (MASKED) {
#pragma unroll
      for (int r = 0; r < 16; ++r) {
        const int jk = kv0 + (kh << 5) + ((r >> 3) << 4) + (hi << 3) + (r & 7);
        if (jk > iq || jk <= iq - WIN) sf[r] = -1e30f;
      }
    }
    // ---- lane-local max over 16 scores ----
    float m0 = fmaxf(sf[0], sf[8]),  m1_ = fmaxf(sf[1], sf[9]);
    float m2 = fmaxf(sf[2], sf[10]), m3 = fmaxf(sf[3], sf[11]);
    float m4 = fmaxf(sf[4], sf[12]), m5 = fmaxf(sf[5], sf[13]);
    float m6 = fmaxf(sf[6], sf[14]), m7 = fmaxf(sf[7], sf[15]);
    m0 = fmaxf(m0, m4); m1_ = fmaxf(m1_, m5); m2 = fmaxf(m2, m6); m3 = fmaxf(m3, m7);
    const float pmax = fmaxf(fmaxf(m0, m1_), fmaxf(m2, m3));
    // ---- T13 defer-max, lane-local gate ----
    if (__any(pmax - m_run > 8.0f)) {
      float rmax = fmaxf(pmax, __shfl_xor(pmax, 32));  // lanes lq/lq+32 share q
      const float mnew = fmaxf(m_run, rmax);
      const float rs = exp2f(m_run - mnew);
      m_run = mnew;
      l_part *= rs;
#pragma unroll
      for (int r = 0; r < 16; ++r) {
        const float rr = __shfl(rs, (r & 3) + ((r >> 2) << 3) + (hi << 2), 32);
        o_acc[0][r] *= rr;
        o_acc[1][r] *= rr;
      }
    }
    // ---- P = exp2(S - m), packed in-register as PV A-frags ----
    union { unsigned short us[8]; bf16x8 v; } pu[2];
    float lloc = 0.0f;
#pragma unroll
    for (int m1 = 0; m1 < 2; ++m1)
#pragma unroll
      for (int e = 0; e < 8; ++e) {
        const float p = exp2f(sf[(m1 << 3) + e] - m_run);
        lloc += p;
        pu[m1].us[e] = f2bf(p);
      }
    l_part += lloc;
    // ---- V B-frags + PV: o[q][d] += P[q][k] V[k][d] ----
    bf16x8 vf[2][2];   // [m1][dt]
#pragma unroll
    for (int m1 = 0; m1 < 2; ++m1)
#pragma unroll
      for (int dt = 0; dt < 2; ++dt) {
        const int base = (((dt << 5) + lq) << 7) + (kh << 6) + (m1 << 5) + (hi << 4);
        vf[m1][dt] = *(const bf16x8*)(sV + (base ^ swz));
      }
    __builtin_amdgcn_s_setprio(1);
#pragma unroll
    for (int dt = 0; dt < 2; ++dt)
#pragma unroll
      for (int m1 = 0; m1 < 2; ++m1)
        o_acc[dt] = __builtin_amdgcn_mfma_f32_32x32x16_bf16(pu[m1].v, vf[m1][dt], o_acc[dt], 0, 0, 0);
    __builtin_amdgcn_s_setprio(0);
  };

  for (int kv0 = lo; kv0 < hi2; kv0 += 64) {
    __syncthreads();   // bufA staged (vmcnt drained at barrier); bufB free
    if (kv0 + 64 < hi2) {
      GLDS16(src0, bufB + dbase);
      GLDS16(src1, bufB + dbase + 1024);
      src0 += sadv; src1 += sadv;
    }
    const bool masked = (kv0 < full_lo) || (kv0 > full_hi);
    if (masked) TILE(kv0, bufA, bufA + 8192, true);
    else        TILE(kv0, bufA, bufA + 8192, false);
    char* tmp = bufA; bufA = bufB; bufB = tmp;
  }

  // ---- epilogue: merge the two key-halves per q-group ----
  const float lsum = l_part + __shfl_xor(l_part, 32);  // halves cover disjoint keys

  __syncthreads();   // all tile reads done; reuse lds as merge scratch
  if (w < 4) {       // kh=0 publish o (f32, 32KB) and (m, l) (1KB)
    char* ob = lds + (qh << 13);
#pragma unroll
    for (int dt = 0; dt < 2; ++dt)
#pragma unroll
      for (int j = 0; j < 4; ++j) {
        f32x4 s4 = { o_acc[dt][4*j], o_acc[dt][4*j+1], o_acc[dt][4*j+2], o_acc[dt][4*j+3] };
        *(f32x4*)(ob + (dt << 12) + (l << 6) + (j << 4)) = s4;
      }
    if (hi == 0) {
      *(float*)(lds + 32768 + (qh << 8) + (lq << 3))     = m_run;
      *(float*)(lds + 32768 + (qh << 8) + (lq << 3) + 4) = lsum;
    }
  }
  __syncthreads();
  if (w >= 4) {      // kh=1 merge + write ctx
    const char* ob = lds + (qh << 13);
    const float m_p = *(const float*)(lds + 32768 + (qh << 8) + (lq << 3));
    const float l_p = *(const float*)(lds + 32768 + (qh << 8) + (lq << 3) + 4);
    const float m_f = fmaxf(m_run, m_p);
    const float a  = exp2f(m_run - m_f);
    const float bb = exp2f(m_p  - m_f);
    const float inv = 1.0f / (a * lsum + bb * l_p);
    const float alpha = a * inv, beta = bb * inv;
    unsigned short* cp = ctx + ((size_t)(b * S_LEN + q0 + (qh << 5))) * D_MODEL + h * HDIM;
#pragma unroll
    for (int dt = 0; dt < 2; ++dt) {
#pragma unroll
      for (int j = 0; j < 4; ++j) {
        const f32x4 op = *(const f32x4*)(ob + (dt << 12) + (l << 6) + (j << 4));
#pragma unroll
        for (int k = 0; k < 4; ++k) {
          const int r = 4*j + k;
          const int qq = (r & 3) + ((r >> 2) << 3) + (hi << 2);
          const float al = __shfl(alpha, qq, 32);
          const float be = __shfl(beta,  qq, 32);
          const float of = al * o_acc[dt][r] + be * op[k];
          cp[(size_t)qq * D_MODEL + (dt << 5) + lq] = f2bf(of);
        }
      }
    }
  }
}

// ---------- launch ----------
extern "C" void kernel_launch(void* const* d_in, const int* in_sizes, int n_in,
                              void* d_out, int out_size, void* d_ws, size_t ws_size,
                              hipStream_t stream)
{
  const float* x    = (const float*)d_in[0];
  const float* Wqkv = (const float*)d_in[1];
  const float* bqkv = (const float*)d_in[2];
  const float* Wout = (const float*)d_in[3];
  const float* bout = (const float*)d_in[4];
  float* out = (float*)d_out;

  char* ws = (char*)d_ws;
  if (ws_size < 62914560u) return;

  unsigned short* xb    = (unsigned short*)(ws);
  unsigned short* ctx   = xb;                                  // alias after gemm1
  unsigned short* wqkvb = (unsigned short*)(ws + 16777216);
  unsigned short* woutb = (unsigned short*)(ws + 29360128);
  unsigned short* Qs    = (unsigned short*)(ws + 37748736);
  unsigned short* Kbuf  = (unsigned short*)(ws + 54525952);
  unsigned short* Vtbuf = (unsigned short*)(ws + 58720256);    // [b][g][d][s]

  cvt3<<<2048, 256, 0, stream>>>(x, xb, MTOT * D_MODEL,
                                 Wqkv, wqkvb, QKV_N * D_MODEL,
                                 Wout, woutb, D_MODEL * D_MODEL);

  gemm_nt<0><<<dim3(QKV_N / 128, MTOT / 128), 256, 0, stream>>>(
      xb, wqkvb, bqkv, D_MODEL, QKV_N, Qs, Kbuf, Vtbuf, nullptr);

  attn_swin<<<dim3(S_LEN / 128, NH, 2), 512, 0, stream>>>(Qs, Kbuf, Vtbuf, ctx);

  gemm_nt<1><<<dim3(D_MODEL / 128, MTOT / 128), 256, 0, stream>>>(
      ctx, woutb, bout, D_MODEL, D_MODEL, nullptr, nullptr, nullptr, out);
}

// Round 15
// 231.742 us; speedup vs baseline: 1.0457x; 1.0457x over previous
//
#include <hip/hip_runtime.h>
#include <stdint.h>

// ---------- problem constants ----------
#define S_LEN   2048
#define D_MODEL 2048
#define NH      32
#define NKV     8
#define HDIM    64
#define WIN     1024
#define QKV_N   3072
#define MTOT    4096          // B*S
#define QSCALE  0.18033688011112042f   // 0.125 * log2(e)

typedef __bf16 bf16x8 __attribute__((ext_vector_type(8)));
typedef float  f32x4  __attribute__((ext_vector_type(4)));
typedef unsigned short u16x8 __attribute__((ext_vector_type(8)));
typedef unsigned short u16x4 __attribute__((ext_vector_type(4)));

#define GLDS16(g, l) __builtin_amdgcn_global_load_lds( \
    (__attribute__((address_space(1))) void*)(g),      \
    (__attribute__((address_space(3))) void*)(l), 16, 0, 0)

__device__ __forceinline__ unsigned short f2bf(float f) {
  __bf16 b = (__bf16)f;
  return __builtin_bit_cast(unsigned short, b);
}

__device__ __forceinline__ void hard_barrier() {
  asm volatile("" ::: "memory");
  __builtin_amdgcn_s_barrier();
  asm volatile("" ::: "memory");
  __builtin_amdgcn_sched_barrier(0);
}

// ---------- fp32 -> bf16 conversion ----------
__global__ void cvt3(const float* __restrict__ s0, unsigned short* __restrict__ d0, int n0,
                     const float* __restrict__ s1, unsigned short* __restrict__ d1, int n1,
                     const float* __restrict__ s2, unsigned short* __restrict__ d2, int n2)
{
  int total4 = (n0 + n1 + n2) >> 2;
  for (int idx = blockIdx.x * blockDim.x + threadIdx.x; idx < total4;
       idx += gridDim.x * blockDim.x) {
    int i = idx << 2;
    const float* s; unsigned short* d;
    if (i < n0)            { s = s0 + i;            d = d0 + i; }
    else if (i < n0 + n1)  { s = s1 + (i - n0);     d = d1 + (i - n0); }
    else                   { s = s2 + (i - n0 - n1); d = d2 + (i - n0 - n1); }
    float4 v = *(const float4*)s;
    u16x4 o;
    o[0] = f2bf(v.x); o[1] = f2bf(v.y); o[2] = f2bf(v.z); o[3] = f2bf(v.w);
    *(u16x4*)d = o;
  }
}

// ---------- 8-phase 256x256x64 GEMM, QKV epilogue ----------
// C[m,e] = sum_k A[m,k]*B[e,k] + bias[e], scattered to Q(scaled)/K/Vt.
// 512 thr = 8 waves (wm=w>>2 in {0,1}: 128 rows; wn=w&3: 64 cols).
// LDS 128KB: region(op,buf,kh) = op*64K + buf*32K + kh*16K, each 16KB
// holding [256 rows][32 k] bf16 row-major (64B stride — m97's proven
// conflict-free layout; GLDS stages it linearly, no swizzle needed).
// Pipeline: pair p/2 computes (buf=p/4, kh=(p/2)&1); each phase stages one
// half-tile into the region freed 2 phases ago; vmcnt(8) at end of every
// odd phase (counted, never 0); raw s_barrier ×2/phase + sched fences.
__global__ __launch_bounds__(512, 2)
void gemm8p_qkv(const unsigned short* __restrict__ A, const unsigned short* __restrict__ Bm,
                const float* __restrict__ bias,
                unsigned short* __restrict__ qo, unsigned short* __restrict__ ko,
                unsigned short* __restrict__ vo)
{
  extern __shared__ char lds[];
  const int K2 = D_MODEL * 2;            // row stride in bytes
  const int t = threadIdx.x, w = t >> 6, l = t & 63;
  const int fr = l & 15, fq = l >> 4;
  const int wm = w >> 2, wn = w & 3;
  const int bm0 = blockIdx.y << 8, bn0 = blockIdx.x << 8;

  // staging: thread covers LDS bytes [t*16, t*16+16) and +8192 of each region
  const int srow = t >> 2;               // 0..127
  const int scol = (t & 3) << 4;         // 0,16,32,48
  const char* aR0 = (const char*)A  + (size_t)(bm0 + srow) * K2 + scol;
  const char* aR1 = aR0 + (size_t)128 * K2;
  const char* bR0 = (const char*)Bm + (size_t)(bn0 + srow) * K2 + scol;
  const char* bR1 = bR0 + (size_t)128 * K2;
  char* ldsW = lds + (w << 10);          // wave-uniform dest base

  f32x4 acc[8][4] = {};

  // ---- prologue: stage T0.k0(A,B), T0.k1(A,B), T1.k0(A,B) ----
  GLDS16(aR0 + 0,   ldsW + 0);          GLDS16(aR1 + 0,   ldsW + 8192);
  GLDS16(bR0 + 0,   ldsW + 65536);      GLDS16(bR1 + 0,   ldsW + 65536 + 8192);
  GLDS16(aR0 + 64,  ldsW + 16384);      GLDS16(aR1 + 64,  ldsW + 16384 + 8192);
  GLDS16(bR0 + 64,  ldsW + 81920);      GLDS16(bR1 + 64,  ldsW + 81920 + 8192);
  GLDS16(aR0 + 128, ldsW + 32768);      GLDS16(aR1 + 128, ldsW + 32768 + 8192);
  GLDS16(bR0 + 128, ldsW + 98304);      GLDS16(bR1 + 128, ldsW + 98304 + 8192);
  asm volatile("s_waitcnt vmcnt(8)" ::: "memory");
  hard_barrier();

  bf16x8 afr[4], bfr[4];
  // stage-target region per phase (A-part; +65536 for B on odd phases)
  // ph0,1: buf1.k1 ; ph2,3: buf0.k0 ; ph4,5: buf0.k1 ; ph6,7: buf1.k0
  constexpr int stBase[4] = { 49152, 0, 16384, 32768 };

  for (int i = 0; i < 16; ++i) {
    const int c0 = i << 8;
#pragma unroll
    for (int p = 0; p < 8; ++p) {
      const int pr = p >> 1;
      const int mh = p & 1;
      const int aLr = ((pr >> 1) << 15) + ((pr & 1) << 14);   // read region (A)
      const int bLr = 65536 + aLr;
      // ---- ds_read fragments ----
      if (mh == 0) {
#pragma unroll
        for (int ni = 0; ni < 4; ++ni)
          bfr[ni] = *(const bf16x8*)(lds + bLr +
              (((wn << 6) + (ni << 4) + fr) << 6) + (fq << 4));
      }
#pragma unroll
      for (int j = 0; j < 4; ++j)
        afr[j] = *(const bf16x8*)(lds + aLr +
            (((wm << 7) + (((mh << 2) + j) << 4) + fr) << 6) + (fq << 4));
      // ---- issue stage of one half-tile ----
      {
        const int coff = c0 + 192 + (pr << 6);   // tile/k-half source col bytes
        const int dst = stBase[pr] + (mh << 16);
        const char* s0 = mh ? bR0 : aR0;
        const char* s1 = mh ? bR1 : aR1;
        GLDS16(s0 + coff, ldsW + dst);
        GLDS16(s1 + coff, ldsW + dst + 8192);
      }
      hard_barrier();                     // all reads+stage-issues aligned
      // ---- MFMA quadrant (compiler inserts lgkmcnt for its own loads) ----
      __builtin_amdgcn_s_setprio(1);
#pragma unroll
      for (int j = 0; j < 4; ++j)
#pragma unroll
        for (int ni = 0; ni < 4; ++ni)
          acc[(mh << 2) + j][ni] = __builtin_amdgcn_mfma_f32_16x16x32_bf16(
              afr[j], bfr[ni], acc[(mh << 2) + j][ni], 0, 0, 0);
      __builtin_amdgcn_s_setprio(0);
      if (mh) asm volatile("s_waitcnt vmcnt(8)" ::: "memory");  // pair-end, counted
      hard_barrier();
    }
  }

  // ---- epilogue: QKV scatter ----
#pragma unroll
  for (int ni = 0; ni < 4; ++ni) {
    const int e = bn0 + (wn << 6) + (ni << 4) + fr;
    const float bs = bias[e];
    const int d = e & 63;
#pragma unroll
    for (int mi = 0; mi < 8; ++mi) {
#pragma unroll
      for (int j = 0; j < 4; ++j) {
        const int m = bm0 + (wm << 7) + (mi << 4) + (fq << 2) + j;
        const int b = m >> 11, s = m & 2047;
        const float v = acc[mi][ni][j] + bs;
        if (e < 2048) {
          const int h = e >> 6;
          qo[(((size_t)b * NH + h) * S_LEN + s) * HDIM + d] = f2bf(v * QSCALE);
        } else if (e < 2560) {
          const int gg = (e - 2048) >> 6;
          ko[(((size_t)b * NKV + gg) * S_LEN + s) * HDIM + d] = f2bf(v);
        } else {
          const int gg = (e - 2560) >> 6;
          vo[(((size_t)b * NKV + gg) * HDIM + d) * S_LEN + s] = f2bf(v);
        }
      }
    }
  }
}

// ---------- NT GEMM (m97 128² structure) — used for the out-projection ----------
template<int EP>
__global__ __launch_bounds__(256)
void gemm_nt(const unsigned short* __restrict__ A, const unsigned short* __restrict__ Bm,
             const float* __restrict__ bias, int K, int N,
             unsigned short* __restrict__ qo, unsigned short* __restrict__ ko,
             unsigned short* __restrict__ vo, float* __restrict__ co)
{
  __shared__ unsigned short sA[128 * 32];
  __shared__ unsigned short sB[128 * 32];
  const int t = threadIdx.x;
  const int l = t & 63;
  const int brow = blockIdx.y << 7;
  const int bcol = blockIdx.x << 7;
  const int wr = ((t >> 7) & 1) << 6;
  const int wc = ((t >> 6) & 1) << 6;

  const int srow  = t >> 2;
  const int skoff = (t & 3) << 3;
  const unsigned short* aP = A + (size_t)(brow + srow) * K + skoff;
  const unsigned short* bP = Bm + (size_t)(bcol + srow) * K + skoff;
  unsigned short* ldsA0 = &sA[(t & 192) << 3];
  unsigned short* ldsA1 = &sA[(256 + (t & 192)) << 3];
  unsigned short* ldsB0 = &sB[(t & 192) << 3];
  unsigned short* ldsB1 = &sB[(256 + (t & 192)) << 3];

  f32x4 acc[4][4] = {};
  const int fr = l & 15;
  const int fk = (l >> 4) << 3;

  for (int kt = 0; kt < K; kt += 32) {
    GLDS16(aP, ldsA0);
    GLDS16(aP + (size_t)64 * K, ldsA1);
    GLDS16(bP, ldsB0);
    GLDS16(bP + (size_t)64 * K, ldsB1);
    aP += 32; bP += 32;
    __syncthreads();

    bf16x8 af[4], bf[4];
#pragma unroll
    for (int mi = 0; mi < 4; ++mi)
      af[mi] = *(const bf16x8*)&sA[(wr + mi * 16 + fr) * 32 + fk];
#pragma unroll
    for (int ni = 0; ni < 4; ++ni)
      bf[ni] = *(const bf16x8*)&sB[(wc + ni * 16 + fr) * 32 + fk];
#pragma unroll
    for (int mi = 0; mi < 4; ++mi)
#pragma unroll
      for (int ni = 0; ni < 4; ++ni)
        acc[mi][ni] = __builtin_amdgcn_mfma_f32_16x16x32_bf16(af[mi], bf[ni], acc[mi][ni], 0, 0, 0);
    __syncthreads();
  }

  const int fq4 = (l >> 4) << 2;
  if (EP == 1) {
#pragma unroll
    for (int mi = 0; mi < 4; ++mi)
#pragma unroll
      for (int j = 0; j < 4; ++j) {
        const int m = brow + wr + mi * 16 + fq4 + j;
#pragma unroll
        for (int ni = 0; ni < 4; ++ni) {
          const int n = bcol + wc + ni * 16 + fr;
          co[(size_t)m * N + n] = acc[mi][ni][j] + bias[n];
        }
      }
  }
}

// ---------- sliding-window flash attention, v10b (round-13 verified, 86 us) ----------
__global__ __launch_bounds__(512)
void attn_swin(const unsigned short* __restrict__ Qs, const unsigned short* __restrict__ Kb,
               const unsigned short* __restrict__ Vtb, unsigned short* __restrict__ ctx)
{
  __shared__ char lds[32768];   // 2 buffers x (K 8KB + V 8KB)

  const int t = threadIdx.x, w = t >> 6, l = t & 63;
  const int fr = l & 15, fq = l >> 4;
  const int qh = w & 3, kh = w >> 2;
  const int q0 = blockIdx.x << 6;
  const int h = blockIdx.y, b = blockIdx.z;
  const int g = h >> 2;

  const unsigned short* qp = Qs + (((size_t)(b * NH + h)) * S_LEN + q0 + (qh << 4)) * HDIM;
  const bf16x8 qf0 = *(const bf16x8*)(qp + fr * HDIM + (fq << 3));
  const bf16x8 qf1 = *(const bf16x8*)(qp + fr * HDIM + 32 + (fq << 3));

  const unsigned short* Kg  = Kb  + ((size_t)(b * NKV + g)) * S_LEN * HDIM;  // [s][d]
  const unsigned short* Vtg = Vtb + ((size_t)(b * NKV + g)) * HDIM * S_LEN;  // [d][s]

  float m_run = -1e30f, l_part = 0.0f;
  f32x4 o_acc[4] = {};

  int lo = q0 - (WIN - 1); if (lo < 0) lo = 0; lo &= ~63;
  const int hi = q0 + 64;
  const int full_lo = q0 - (WIN - 64);
  const int full_hi = q0 - 64;

  const unsigned short* src0;
  const unsigned short* src1;
  {
    const int x0 = ((w & 3) << 11) + (l << 4);
    const int x1 = x0 + 1024;
    if (w < 4) {
      const int s0 = x0 >> 7, o0 = ((x0 >> 4) & 7) ^ (s0 & 7);
      const int s1 = x1 >> 7, o1 = ((x1 >> 4) & 7) ^ (s1 & 7);
      const int p0 = ((s0 >> 5) << 5) | (((s0 >> 2) & 3) << 3) | (((s0 >> 4) & 1) << 2) | (s0 & 3);
      const int p1 = ((s1 >> 5) << 5) | (((s1 >> 2) & 3) << 3) | (((s1 >> 4) & 1) << 2) | (s1 & 3);
      src0 = Kg + (size_t)(lo + p0) * HDIM + (o0 << 3);
      src1 = Kg + (size_t)(lo + p1) * HDIM + (o1 << 3);
    } else {
      const int d0 = x0 >> 7, o0 = ((x0 >> 4) & 7) ^ (d0 & 7);
      const int d1 = x1 >> 7, o1 = ((x1 >> 4) & 7) ^ (d1 & 7);
      src0 = Vtg + (size_t)d0 * S_LEN + lo + (o0 << 3);
      src1 = Vtg + (size_t)d1 * S_LEN + lo + (o1 << 3);
    }
  }
  const int sadv = (w < 4) ? 64 * HDIM : 64;
  const int dbase = ((w < 4) ? 0 : 8192) + ((w & 3) << 11) + (l << 4);

  char* bufA = lds;
  char* bufB = lds + 16384;

  GLDS16(src0, bufA + dbase);
  GLDS16(src1, bufA + dbase + 1024);
  src0 += sadv; src1 += sadv;

  const int iq = q0 + (qh << 4) + fr;
  const int swr = (fr & 7) << 4;

  auto TILE = [&](int kv0, const char* sK, const char* sV, bool MASKED)
      __attribute__((always_inline)) {
    bf16x8 kf[2][2];
#pragma unroll
    for (int ntg = 0; ntg < 2; ++ntg) {
      const int slot = (kh << 5) + (ntg << 4) + fr;
      kf[ntg][0] = *(const bf16x8*)(sK + (((slot << 7) + (fq << 4)) ^ swr));
      kf[ntg][1] = *(const bf16x8*)(sK + (((slot << 7) + ((fq + 4) << 4)) ^ swr));
    }
    __builtin_amdgcn_s_setprio(1);
    f32x4 sf[2];
#pragma unroll
    for (int ntg = 0; ntg < 2; ++ntg) {
      f32x4 z = {};
      z = __builtin_amdgcn_mfma_f32_16x16x32_bf16(kf[ntg][0], qf0, z, 0, 0, 0);
      z = __builtin_amdgcn_mfma_f32_16x16x32_bf16(kf[ntg][1], qf1, z, 0, 0, 0);
      sf[ntg] = z;
    }
    __builtin_amdgcn_s_setprio(0);
    if (MASKED) {
#pragma unroll
      for (int ntg = 0; ntg < 2; ++ntg)
#pragma unroll
        for (int r = 0; r < 4; ++r) {
          const int jk = kv0 + (kh << 5) + (fq << 3) + (ntg << 2) + r;
          if (jk > iq || jk <= iq - WIN) sf[ntg][r] = -1e30f;
        }
    }
    float pmax;
    {
      f32x4 mx = sf[0];
      mx[0] = fmaxf(mx[0], sf[1][0]); mx[1] = fmaxf(mx[1], sf[1][1]);
      mx[2] = fmaxf(mx[2], sf[1][2]); mx[3] = fmaxf(mx[3], sf[1][3]);
      pmax = fmaxf(fmaxf(mx[0], mx[1]), fmaxf(mx[2], mx[3]));
    }
    if (__any(pmax - m_run > 8.0f)) {
      float rmax = fmaxf(pmax, __shfl_xor(pmax, 16));
      rmax = fmaxf(rmax, __shfl_xor(rmax, 32));
      const float mnew = fmaxf(m_run, rmax);
      const float rs = exp2f(m_run - mnew);
      m_run = mnew;
      l_part *= rs;
      float rs_o[4];
#pragma unroll
      for (int r = 0; r < 4; ++r) rs_o[r] = __shfl(rs, (fq << 2) + r, 16);
#pragma unroll
      for (int dt = 0; dt < 4; ++dt)
#pragma unroll
        for (int r = 0; r < 4; ++r) o_acc[dt][r] *= rs_o[r];
    }
    union { unsigned short us[8]; bf16x8 v; } pu;
    float lloc = 0.0f;
#pragma unroll
    for (int ntg = 0; ntg < 2; ++ntg)
#pragma unroll
      for (int r = 0; r < 4; ++r) {
        const float p = exp2f(sf[ntg][r] - m_run);
        lloc += p;
        pu.us[(ntg << 2) + r] = f2bf(p);
      }
    l_part += lloc;
    bf16x8 vf[4];
#pragma unroll
    for (int dt = 0; dt < 4; ++dt) {
      const int d = (dt << 4) + fr;
      vf[dt] = *(const bf16x8*)(sV + ((d << 7) + ((((kh << 2) + fq) ^ (fr & 7)) << 4)));
    }
    __builtin_amdgcn_s_setprio(1);
#pragma unroll
    for (int dt = 0; dt < 4; ++dt)
      o_acc[dt] = __builtin_amdgcn_mfma_f32_16x16x32_bf16(pu.v, vf[dt], o_acc[dt], 0, 0, 0);
    __builtin_amdgcn_s_setprio(0);
  };

  for (int kv0 = lo; kv0 < hi; kv0 += 64) {
    __syncthreads();
    if (kv0 + 64 < hi) {
      GLDS16(src0, bufB + dbase);
      GLDS16(src1, bufB + dbase + 1024);
      src0 += sadv; src1 += sadv;
    }
    const bool masked = (kv0 < full_lo) || (kv0 > full_hi);
    if (masked) TILE(kv0, bufA, bufA + 8192, true);
    else        TILE(kv0, bufA, bufA + 8192, false);
    char* tmp = bufA; bufA = bufB; bufB = tmp;
  }

  float lsum = l_part;
  lsum += __shfl_xor(lsum, 16);
  lsum += __shfl_xor(lsum, 32);

  __syncthreads();
  if (w < 4) {
    char* ob = lds + ((w & 3) << 12);
#pragma unroll
    for (int dt = 0; dt < 4; ++dt)
      *(f32x4*)(ob + (dt << 10) + (l << 4)) = o_acc[dt];
    if (fq == 0) {
      *(float*)(lds + 16384 + ((w & 3) << 7) + (fr << 3))     = m_run;
      *(float*)(lds + 16384 + ((w & 3) << 7) + (fr << 3) + 4) = lsum;
    }
  }
  __syncthreads();
  if (w >= 4) {
    const char* ob = lds + ((w & 3) << 12);
    const float m_p = *(const float*)(lds + 16384 + ((w & 3) << 7) + (fr << 3));
    const float l_p = *(const float*)(lds + 16384 + ((w & 3) << 7) + (fr << 3) + 4);
    const float m_f = fmaxf(m_run, m_p);
    const float a  = exp2f(m_run - m_f);
    const float bb = exp2f(m_p  - m_f);
    const float inv = 1.0f / (a * lsum + bb * l_p);
    const float alpha = a * inv, beta = bb * inv;
    float al[4], be[4];
#pragma unroll
    for (int r = 0; r < 4; ++r) {
      al[r] = __shfl(alpha, (fq << 2) + r, 16);
      be[r] = __shfl(beta,  (fq << 2) + r, 16);
    }
    unsigned short* cp = ctx + ((size_t)(b * S_LEN + q0 + (qh << 4))) * D_MODEL + h * HDIM;
#pragma unroll
    for (int dt = 0; dt < 4; ++dt) {
      const f32x4 op = *(const f32x4*)(ob + (dt << 10) + (l << 4));
#pragma unroll
      for (int r = 0; r < 4; ++r) {
        const float of = al[r] * o_acc[dt][r] + be[r] * op[r];
        cp[(size_t)((fq << 2) + r) * D_MODEL + (dt << 4) + fr] = f2bf(of);
      }
    }
  }
}

// ---------- launch ----------
extern "C" void kernel_launch(void* const* d_in, const int* in_sizes, int n_in,
                              void* d_out, int out_size, void* d_ws, size_t ws_size,
                              hipStream_t stream)
{
  const float* x    = (const float*)d_in[0];
  const float* Wqkv = (const float*)d_in[1];
  const float* bqkv = (const float*)d_in[2];
  const float* Wout = (const float*)d_in[3];
  const float* bout = (const float*)d_in[4];
  float* out = (float*)d_out;

  char* ws = (char*)d_ws;
  if (ws_size < 62914560u) return;

  unsigned short* xb    = (unsigned short*)(ws);
  unsigned short* ctx   = xb;                                  // alias after gemm1
  unsigned short* wqkvb = (unsigned short*)(ws + 16777216);
  unsigned short* woutb = (unsigned short*)(ws + 29360128);
  unsigned short* Qs    = (unsigned short*)(ws + 37748736);
  unsigned short* Kbuf  = (unsigned short*)(ws + 54525952);
  unsigned short* Vtbuf = (unsigned short*)(ws + 58720256);    // [b][g][d][s]

  (void)hipFuncSetAttribute((const void*)gemm8p_qkv,
                            hipFuncAttributeMaxDynamicSharedMemorySize, 131072);

  cvt3<<<2048, 256, 0, stream>>>(x, xb, MTOT * D_MODEL,
                                 Wqkv, wqkvb, QKV_N * D_MODEL,
                                 Wout, woutb, D_MODEL * D_MODEL);

  gemm8p_qkv<<<dim3(QKV_N / 256, MTOT / 256), 512, 131072, stream>>>(
      xb, wqkvb, bqkv, Qs, Kbuf, Vtbuf);

  attn_swin<<<dim3(S_LEN / 64, NH, 2), 512, 0, stream>>>(Qs, Kbuf, Vtbuf, ctx);

  gemm_nt<1><<<dim3(D_MODEL / 128, MTOT / 128), 256, 0, stream>>>(
      ctx, woutb, bout, D_MODEL, D_MODEL, nullptr, nullptr, nullptr, out);
}

// Round 16
// 219.908 us; speedup vs baseline: 1.1019x; 1.0538x over previous
//
#include <hip/hip_runtime.h>
#include <stdint.h>

// ---------- problem constants ----------
#define S_LEN   2048
#define D_MODEL 2048
#define NH      32
#define NKV     8
#define HDIM    64
#define WIN     1024
#define QKV_N   3072
#define MTOT    4096          // B*S
#define QSCALE  0.18033688011112042f   // 0.125 * log2(e)

typedef __bf16 bf16x8 __attribute__((ext_vector_type(8)));
typedef float  f32x4  __attribute__((ext_vector_type(4)));
typedef unsigned short u16x8 __attribute__((ext_vector_type(8)));
typedef unsigned short u16x4 __attribute__((ext_vector_type(4)));

#define GLDS16(g, l) __builtin_amdgcn_global_load_lds( \
    (__attribute__((address_space(1))) void*)(g),      \
    (__attribute__((address_space(3))) void*)(l), 16, 0, 0)

// RNE f32->bf16 via the compiler cast (v_cvt_pk fusion).
__device__ __forceinline__ unsigned short f2bf(float f) {
  __bf16 b = (__bf16)f;
  return __builtin_bit_cast(unsigned short, b);
}

// ---------- fp32 -> bf16 conversion ----------
__global__ void cvt3(const float* __restrict__ s0, unsigned short* __restrict__ d0, int n0,
                     const float* __restrict__ s1, unsigned short* __restrict__ d1, int n1,
                     const float* __restrict__ s2, unsigned short* __restrict__ d2, int n2)
{
  int total4 = (n0 + n1 + n2) >> 2;
  for (int idx = blockIdx.x * blockDim.x + threadIdx.x; idx < total4;
       idx += gridDim.x * blockDim.x) {
    int i = idx << 2;
    const float* s; unsigned short* d;
    if (i < n0)            { s = s0 + i;            d = d0 + i; }
    else if (i < n0 + n1)  { s = s1 + (i - n0);     d = d1 + (i - n0); }
    else                   { s = s2 + (i - n0 - n1); d = d2 + (i - n0 - n1); }
    float4 v = *(const float4*)s;
    u16x4 o;
    o[0] = f2bf(v.x); o[1] = f2bf(v.y); o[2] = f2bf(v.z); o[3] = f2bf(v.w);
    *(u16x4*)d = o;
  }
}

// ---------- NT GEMM: C[m,n] = sum_k A[m,k]*B[n,k] (+bias) ----------
// m97 128² structure. EP==0: QKV epilogue via per-wave LDS transpose ->
// all global writes are coalesced 16B chunks (1KB/pass/wave). EP==1: fp32 out.
template<int EP>
__global__ __launch_bounds__(256)
void gemm_nt(const unsigned short* __restrict__ A, const unsigned short* __restrict__ Bm,
             const float* __restrict__ bias, int K, int N,
             unsigned short* __restrict__ qo, unsigned short* __restrict__ ko,
             unsigned short* __restrict__ vo, float* __restrict__ co)
{
  __shared__ __align__(16) char smem[(EP == 0) ? 36864 : 16384];
  unsigned short* sA = (unsigned short*)smem;
  unsigned short* sB = (unsigned short*)(smem + 8192);

  const int t = threadIdx.x;
  const int l = t & 63;
  const int brow = blockIdx.y << 7;
  const int bcol = blockIdx.x << 7;
  const int wr = ((t >> 7) & 1) << 6;
  const int wc = ((t >> 6) & 1) << 6;

  const int srow  = t >> 2;
  const int skoff = (t & 3) << 3;
  const unsigned short* aP = A + (size_t)(brow + srow) * K + skoff;
  const unsigned short* bP = Bm + (size_t)(bcol + srow) * K + skoff;
  unsigned short* ldsA0 = sA + ((t & 192) << 3);
  unsigned short* ldsA1 = sA + ((256 + (t & 192)) << 3);
  unsigned short* ldsB0 = sB + ((t & 192) << 3);
  unsigned short* ldsB1 = sB + ((256 + (t & 192)) << 3);

  f32x4 acc[4][4] = {};
  const int fr = l & 15;
  const int fk = (l >> 4) << 3;

  for (int kt = 0; kt < K; kt += 32) {
    GLDS16(aP, ldsA0);
    GLDS16(aP + (size_t)64 * K, ldsA1);
    GLDS16(bP, ldsB0);
    GLDS16(bP + (size_t)64 * K, ldsB1);
    aP += 32; bP += 32;
    __syncthreads();

    bf16x8 af[4], bf[4];
#pragma unroll
    for (int mi = 0; mi < 4; ++mi)
      af[mi] = *(const bf16x8*)&sA[(wr + mi * 16 + fr) * 32 + fk];
#pragma unroll
    for (int ni = 0; ni < 4; ++ni)
      bf[ni] = *(const bf16x8*)&sB[(wc + ni * 16 + fr) * 32 + fk];
#pragma unroll
    for (int mi = 0; mi < 4; ++mi)
#pragma unroll
      for (int ni = 0; ni < 4; ++ni)
        acc[mi][ni] = __builtin_amdgcn_mfma_f32_16x16x32_bf16(af[mi], bf[ni], acc[mi][ni], 0, 0, 0);
    __syncthreads();   // final sync: all LDS reads done -> smem reusable
  }

  const int fq4 = (l >> 4) << 2;
  if (EP == 0) {
    // ---- per-wave LDS-transpose epilogue ----
    const int w2 = t >> 6;
    const int e0 = bcol + wc;            // wave's 64-aligned e-range (one head)
    const int m0 = brow + wr;            // wave's 64-aligned m-range (one batch)
    const int bidx = m0 >> 11, s0 = m0 & 2047;
    unsigned short* tile = (unsigned short*)smem + w2 * (64 * 72);
    const float sc = (e0 < 2048) ? QSCALE : 1.0f;
    const bool isV = (e0 >= 2560);
#pragma unroll
    for (int ni = 0; ni < 4; ++ni) {
      const int dd = ni * 16 + fr;
      const float bs = bias[e0 + dd];
#pragma unroll
      for (int mi = 0; mi < 4; ++mi)
#pragma unroll
        for (int j = 0; j < 4; ++j) {
          const int mm = mi * 16 + fq4 + j;
          const float v = (acc[mi][ni][j] + bs) * sc;
          if (isV) tile[dd * 72 + mm] = f2bf(v);   // V: [d][m] (transposed)
          else     tile[mm * 72 + dd] = f2bf(v);   // Q/K: [m][d]
        }
    }
    // same-wave DS ordering: no barrier needed before read-back
    const int lr = l >> 3, lc = l & 7;
    unsigned short* gbase;
    size_t rstride;
    if (e0 < 2048) {
      gbase = qo + (((size_t)bidx * NH + (e0 >> 6)) * S_LEN + s0) * HDIM;
      rstride = HDIM;
    } else if (e0 < 2560) {
      gbase = ko + (((size_t)bidx * NKV + ((e0 - 2048) >> 6)) * S_LEN + s0) * HDIM;
      rstride = HDIM;
    } else {
      gbase = vo + (((size_t)bidx * NKV + ((e0 - 2560) >> 6)) * HDIM) * (size_t)S_LEN + s0;
      rstride = S_LEN;
    }
#pragma unroll
    for (int p = 0; p < 8; ++p) {
      const int row = p * 8 + lr;
      u16x8 vv = *(const u16x8*)&tile[row * 72 + lc * 8];
      *(u16x8*)(gbase + (size_t)row * rstride + lc * 8) = vv;  // 1KB/pass coalesced
    }
  } else {
#pragma unroll
    for (int mi = 0; mi < 4; ++mi)
#pragma unroll
      for (int j = 0; j < 4; ++j) {
        const int m = brow + wr + mi * 16 + fq4 + j;
#pragma unroll
        for (int ni = 0; ni < 4; ++ni) {
          const int n = bcol + wc + ni * 16 + fr;
          co[(size_t)m * N + n] = acc[mi][ni][j] + bias[n];
        }
      }
  }
}

// ---------- sliding-window flash attention, v10b (round-13 verified, 86 us) ----------
__global__ __launch_bounds__(512)
void attn_swin(const unsigned short* __restrict__ Qs, const unsigned short* __restrict__ Kb,
               const unsigned short* __restrict__ Vtb, unsigned short* __restrict__ ctx)
{
  __shared__ char lds[32768];   // 2 buffers x (K 8KB + V 8KB)

  const int t = threadIdx.x, w = t >> 6, l = t & 63;
  const int fr = l & 15, fq = l >> 4;
  const int qh = w & 3, kh = w >> 2;
  const int q0 = blockIdx.x << 6;
  const int h = blockIdx.y, b = blockIdx.z;
  const int g = h >> 2;

  const unsigned short* qp = Qs + (((size_t)(b * NH + h)) * S_LEN + q0 + (qh << 4)) * HDIM;
  const bf16x8 qf0 = *(const bf16x8*)(qp + fr * HDIM + (fq << 3));
  const bf16x8 qf1 = *(const bf16x8*)(qp + fr * HDIM + 32 + (fq << 3));

  const unsigned short* Kg  = Kb  + ((size_t)(b * NKV + g)) * S_LEN * HDIM;  // [s][d]
  const unsigned short* Vtg = Vtb + ((size_t)(b * NKV + g)) * HDIM * S_LEN;  // [d][s]

  float m_run = -1e30f, l_part = 0.0f;
  f32x4 o_acc[4] = {};

  int lo = q0 - (WIN - 1); if (lo < 0) lo = 0; lo &= ~63;
  const int hi = q0 + 64;
  const int full_lo = q0 - (WIN - 64);
  const int full_hi = q0 - 64;

  const unsigned short* src0;
  const unsigned short* src1;
  {
    const int x0 = ((w & 3) << 11) + (l << 4);
    const int x1 = x0 + 1024;
    if (w < 4) {
      const int s0 = x0 >> 7, o0 = ((x0 >> 4) & 7) ^ (s0 & 7);
      const int s1 = x1 >> 7, o1 = ((x1 >> 4) & 7) ^ (s1 & 7);
      const int p0 = ((s0 >> 5) << 5) | (((s0 >> 2) & 3) << 3) | (((s0 >> 4) & 1) << 2) | (s0 & 3);
      const int p1 = ((s1 >> 5) << 5) | (((s1 >> 2) & 3) << 3) | (((s1 >> 4) & 1) << 2) | (s1 & 3);
      src0 = Kg + (size_t)(lo + p0) * HDIM + (o0 << 3);
      src1 = Kg + (size_t)(lo + p1) * HDIM + (o1 << 3);
    } else {
      const int d0 = x0 >> 7, o0 = ((x0 >> 4) & 7) ^ (d0 & 7);
      const int d1 = x1 >> 7, o1 = ((x1 >> 4) & 7) ^ (d1 & 7);
      src0 = Vtg + (size_t)d0 * S_LEN + lo + (o0 << 3);
      src1 = Vtg + (size_t)d1 * S_LEN + lo + (o1 << 3);
    }
  }
  const int sadv = (w < 4) ? 64 * HDIM : 64;
  const int dbase = ((w < 4) ? 0 : 8192) + ((w & 3) << 11) + (l << 4);

  char* bufA = lds;
  char* bufB = lds + 16384;

  GLDS16(src0, bufA + dbase);
  GLDS16(src1, bufA + dbase + 1024);
  src0 += sadv; src1 += sadv;

  const int iq = q0 + (qh << 4) + fr;
  const int swr = (fr & 7) << 4;

  auto TILE = [&](int kv0, const char* sK, const char* sV, bool MASKED)
      __attribute__((always_inline)) {
    bf16x8 kf[2][2];
#pragma unroll
    for (int ntg = 0; ntg < 2; ++ntg) {
      const int slot = (kh << 5) + (ntg << 4) + fr;
      kf[ntg][0] = *(const bf16x8*)(sK + (((slot << 7) + (fq << 4)) ^ swr));
      kf[ntg][1] = *(const bf16x8*)(sK + (((slot << 7) + ((fq + 4) << 4)) ^ swr));
    }
    __builtin_amdgcn_s_setprio(1);
    f32x4 sf[2];
#pragma unroll
    for (int ntg = 0; ntg < 2; ++ntg) {
      f32x4 z = {};
      z = __builtin_amdgcn_mfma_f32_16x16x32_bf16(kf[ntg][0], qf0, z, 0, 0, 0);
      z = __builtin_amdgcn_mfma_f32_16x16x32_bf16(kf[ntg][1], qf1, z, 0, 0, 0);
      sf[ntg] = z;
    }
    __builtin_amdgcn_s_setprio(0);
    if (MASKED) {
#pragma unroll
      for (int ntg = 0; ntg < 2; ++ntg)
#pragma unroll
        for (int r = 0; r < 4; ++r) {
          const int jk = kv0 + (kh << 5) + (fq << 3) + (ntg << 2) + r;
          if (jk > iq || jk <= iq - WIN) sf[ntg][r] = -1e30f;
        }
    }
    float pmax;
    {
      f32x4 mx = sf[0];
      mx[0] = fmaxf(mx[0], sf[1][0]); mx[1] = fmaxf(mx[1], sf[1][1]);
      mx[2] = fmaxf(mx[2], sf[1][2]); mx[3] = fmaxf(mx[3], sf[1][3]);
      pmax = fmaxf(fmaxf(mx[0], mx[1]), fmaxf(mx[2], mx[3]));
    }
    if (__any(pmax - m_run > 8.0f)) {
      float rmax = fmaxf(pmax, __shfl_xor(pmax, 16));
      rmax = fmaxf(rmax, __shfl_xor(rmax, 32));
      const float mnew = fmaxf(m_run, rmax);
      const float rs = exp2f(m_run - mnew);
      m_run = mnew;
      l_part *= rs;
      float rs_o[4];
#pragma unroll
      for (int r = 0; r < 4; ++r) rs_o[r] = __shfl(rs, (fq << 2) + r, 16);
#pragma unroll
      for (int dt = 0; dt < 4; ++dt)
#pragma unroll
        for (int r = 0; r < 4; ++r) o_acc[dt][r] *= rs_o[r];
    }
    union { unsigned short us[8]; bf16x8 v; } pu;
    float lloc = 0.0f;
#pragma unroll
    for (int ntg = 0; ntg < 2; ++ntg)
#pragma unroll
      for (int r = 0; r < 4; ++r) {
        const float p = exp2f(sf[ntg][r] - m_run);
        lloc += p;
        pu.us[(ntg << 2) + r] = f2bf(p);
      }
    l_part += lloc;
    bf16x8 vf[4];
#pragma unroll
    for (int dt = 0; dt < 4; ++dt) {
      const int d = (dt << 4) + fr;
      vf[dt] = *(const bf16x8*)(sV + ((d << 7) + ((((kh << 2) + fq) ^ (fr & 7)) << 4)));
    }
    __builtin_amdgcn_s_setprio(1);
#pragma unroll
    for (int dt = 0; dt < 4; ++dt)
      o_acc[dt] = __builtin_amdgcn_mfma_f32_16x16x32_bf16(pu.v, vf[dt], o_acc[dt], 0, 0, 0);
    __builtin_amdgcn_s_setprio(0);
  };

  for (int kv0 = lo; kv0 < hi; kv0 += 64) {
    __syncthreads();
    if (kv0 + 64 < hi) {
      GLDS16(src0, bufB + dbase);
      GLDS16(src1, bufB + dbase + 1024);
      src0 += sadv; src1 += sadv;
    }
    const bool masked = (kv0 < full_lo) || (kv0 > full_hi);
    if (masked) TILE(kv0, bufA, bufA + 8192, true);
    else        TILE(kv0, bufA, bufA + 8192, false);
    char* tmp = bufA; bufA = bufB; bufB = tmp;
  }

  float lsum = l_part;
  lsum += __shfl_xor(lsum, 16);
  lsum += __shfl_xor(lsum, 32);

  __syncthreads();
  if (w < 4) {
    char* ob = lds + ((w & 3) << 12);
#pragma unroll
    for (int dt = 0; dt < 4; ++dt)
      *(f32x4*)(ob + (dt << 10) + (l << 4)) = o_acc[dt];
    if (fq == 0) {
      *(float*)(lds + 16384 + ((w & 3) << 7) + (fr << 3))     = m_run;
      *(float*)(lds + 16384 + ((w & 3) << 7) + (fr << 3) + 4) = lsum;
    }
  }
  __syncthreads();
  if (w >= 4) {
    const char* ob = lds + ((w & 3) << 12);
    const float m_p = *(const float*)(lds + 16384 + ((w & 3) << 7) + (fr << 3));
    const float l_p = *(const float*)(lds + 16384 + ((w & 3) << 7) + (fr << 3) + 4);
    const float m_f = fmaxf(m_run, m_p);
    const float a  = exp2f(m_run - m_f);
    const float bb = exp2f(m_p  - m_f);
    const float inv = 1.0f / (a * lsum + bb * l_p);
    const float alpha = a * inv, beta = bb * inv;
    float al[4], be[4];
#pragma unroll
    for (int r = 0; r < 4; ++r) {
      al[r] = __shfl(alpha, (fq << 2) + r, 16);
      be[r] = __shfl(beta,  (fq << 2) + r, 16);
    }
    unsigned short* cp = ctx + ((size_t)(b * S_LEN + q0 + (qh << 4))) * D_MODEL + h * HDIM;
#pragma unroll
    for (int dt = 0; dt < 4; ++dt) {
      const f32x4 op = *(const f32x4*)(ob + (dt << 10) + (l << 4));
#pragma unroll
      for (int r = 0; r < 4; ++r) {
        const float of = al[r] * o_acc[dt][r] + be[r] * op[r];
        cp[(size_t)((fq << 2) + r) * D_MODEL + (dt << 4) + fr] = f2bf(of);
      }
    }
  }
}

// ---------- launch ----------
extern "C" void kernel_launch(void* const* d_in, const int* in_sizes, int n_in,
                              void* d_out, int out_size, void* d_ws, size_t ws_size,
                              hipStream_t stream)
{
  const float* x    = (const float*)d_in[0];
  const float* Wqkv = (const float*)d_in[1];
  const float* bqkv = (const float*)d_in[2];
  const float* Wout = (const float*)d_in[3];
  const float* bout = (const float*)d_in[4];
  float* out = (float*)d_out;

  char* ws = (char*)d_ws;
  if (ws_size < 62914560u) return;

  unsigned short* xb    = (unsigned short*)(ws);
  unsigned short* ctx   = xb;                                  // alias after gemm1
  unsigned short* wqkvb = (unsigned short*)(ws + 16777216);
  unsigned short* woutb = (unsigned short*)(ws + 29360128);
  unsigned short* Qs    = (unsigned short*)(ws + 37748736);
  unsigned short* Kbuf  = (unsigned short*)(ws + 54525952);
  unsigned short* Vtbuf = (unsigned short*)(ws + 58720256);    // [b][g][d][s]

  cvt3<<<2048, 256, 0, stream>>>(x, xb, MTOT * D_MODEL,
                                 Wqkv, wqkvb, QKV_N * D_MODEL,
                                 Wout, woutb, D_MODEL * D_MODEL);

  gemm_nt<0><<<dim3(QKV_N / 128, MTOT / 128), 256, 0, stream>>>(
      xb, wqkvb, bqkv, D_MODEL, QKV_N, Qs, Kbuf, Vtbuf, nullptr);

  attn_swin<<<dim3(S_LEN / 64, NH, 2), 512, 0, stream>>>(Qs, Kbuf, Vtbuf, ctx);

  gemm_nt<1><<<dim3(D_MODEL / 128, MTOT / 128), 256, 0, stream>>>(
      ctx, woutb, bout, D_MODEL, D_MODEL, nullptr, nullptr, nullptr, out);
}